// Round 10
// baseline (55.397 us; speedup 1.0000x reference)
//
#include <hip/hip_runtime.h>

#define NQ 12
#define NSTATE (1 << NQ)   // 4096 amps per batch element
#define NL 6
#define TPB 512            // 8 amp-slots/thread; TWO batch elements per slot

// Two batch elements per f4 LDS slot: (reA, imA, reB, imB) -> ds_*_b128.
// Scalar v_fma butterflies (FP32 pipe is scalar-rate on CDNA4; packed fp32 is
// half-throughput per inst, no FLOP gain). Gate constants broadcast via
// v_readlane -> SGPR operands. LDS layout phys = swz(i) = i ^ ((i>>4)&0xF);
// CNOT-chain Gray perm new[i]=old[g(i)], g(i)=i^(i>>1), applied as g^-1
// scatter at pass-D store. All addressing is precomputed BYTE bases + one XOR
// (pass A: pure additive offset-immediate).

typedef float f4 __attribute__((ext_vector_type(4)));

struct A2 { float ar, ai, br, bi; };   // element A and B of one amp slot

__device__ __forceinline__ float RL(float v, int idx) {
    return __int_as_float(__builtin_amdgcn_readlane(__float_as_int(v), idx));
}

// Rot(phi,theta,omega): u00=(A,-B) u01=(-C,-D) u10=(C,-D) u11=(A,B)
__device__ __forceinline__ void bf2(A2& s0, A2& s1,
                                    float A, float B, float C, float D) {
    float n0r, n0i, n1r, n1i;
    n0r = fmaf(A, s0.ar, fmaf( B, s0.ai, fmaf(-C, s1.ar,  D * s1.ai)));
    n0i = fmaf(A, s0.ai, fmaf(-B, s0.ar, fmaf(-C, s1.ai, -D * s1.ar)));
    n1r = fmaf(C, s0.ar, fmaf( D, s0.ai, fmaf( A, s1.ar, -B * s1.ai)));
    n1i = fmaf(C, s0.ai, fmaf(-D, s0.ar, fmaf( A, s1.ai,  B * s1.ar)));
    s0.ar = n0r; s0.ai = n0i; s1.ar = n1r; s1.ai = n1i;
    n0r = fmaf(A, s0.br, fmaf( B, s0.bi, fmaf(-C, s1.br,  D * s1.bi)));
    n0i = fmaf(A, s0.bi, fmaf(-B, s0.br, fmaf(-C, s1.bi, -D * s1.br)));
    n1r = fmaf(C, s0.br, fmaf( D, s0.bi, fmaf( A, s1.br, -B * s1.bi)));
    n1i = fmaf(C, s0.bi, fmaf(-D, s0.br, fmaf( A, s1.bi,  B * s1.br)));
    s0.br = n0r; s0.bi = n0i; s1.br = n1r; s1.bi = n1i;
}

#define BF(i,j) bf2(a##i, a##j, A, B, C, D)
#define PK0 BF(0,1); BF(2,3); BF(4,5); BF(6,7);
#define PK1 BF(0,2); BF(1,3); BF(4,6); BF(5,7);
#define PK2 BF(0,4); BF(1,5); BF(2,6); BF(3,7);
#define GATE(qq, P) { const int gi = gb + (qq); \
    const float A = RL(uA, gi), B = RL(uB, gi), \
                C = RL(uC, gi), D = RL(uD, gi); P }

#define LDS4(off) (*(f4*)((char*)st + (off)))
#define LD1(r, ADR) { f4 v = LDS4(ADR(r)); \
    a##r.ar = v.x; a##r.ai = v.y; a##r.br = v.z; a##r.bi = v.w; }
#define ST1(r, ADR) { f4 v = {a##r.ar, a##r.ai, a##r.br, a##r.bi}; \
    LDS4(ADR(r)) = v; }
#define LD8(ADR) { LD1(0,ADR) LD1(1,ADR) LD1(2,ADR) LD1(3,ADR) \
                   LD1(4,ADR) LD1(5,ADR) LD1(6,ADR) LD1(7,ADR) }
#define ST8(ADR) { ST1(0,ADR) ST1(1,ADR) ST1(2,ADR) ST1(3,ADR) \
                   ST1(4,ADR) ST1(5,ADR) ST1(6,ADR) ST1(7,ADR) }

// Byte-address tilings (i = logical index, t = 9-bit thread, r = 3-bit reg):
// A: i=(r<<9)|t   B: i=t[8:6]<<9|r<<6|t[5:0]   C: i=t[8:3]<<6|r<<3|t[2:0]
// D: i=(t<<3)|r   D-scatter: phys = swz(g^-1(i))
#define ADRA(r)  (ptAb + ((r) << 13))                   // ds offset-immediate
#define ADRB(r)  (ptBb ^ (((r) << 10) ^ (((r) & 3) << 6)))
#define ADRC(r)  (ptCb ^ (((r) << 7) ^ (((r) >> 1) << 4)))
#define ADRD(r)  (ptDb ^ ((r) << 4))
#define GINV3(r) ((r) ^ ((r) >> 1) ^ ((r) >> 2))
#define ADRDS(r) (ptDSb ^ (GINV3(r) << 4))

#define INITA(r) { const float m = mlow * f##r; \
    const int pc = (pcl + __popc(r)) & 3; \
    a##r.ar = (pc==0) ? m : ((pc==2) ? -m : 0.0f); \
    a##r.ai = (pc==1) ? -m : ((pc==3) ? m : 0.0f); }
#define INITB(r) { const float m = mlow * f##r; \
    const int pc = (pcl + __popc(r)) & 3; \
    a##r.br = (pc==0) ? m : ((pc==2) ? -m : 0.0f); \
    a##r.bi = (pc==1) ? -m : ((pc==3) ? m : 0.0f); }

__global__ __launch_bounds__(TPB) void qsim_kernel(
    const float* __restrict__ x,      // (B, 12)
    const float* __restrict__ w,      // (6, 12, 3)
    const float* __restrict__ hw,     // (2, 1)
    const float* __restrict__ hb,     // (2,)
    float* __restrict__ out)          // (B, 2)
{
    __shared__ f4 st[NSTATE];         // 64 KB: both elements, packed per slot

    const int t    = threadIdx.x;     // 9 bits
    const int lane = t & 63;
    const int e0   = blockIdx.x * 2;  // first batch element of this block

    // ---- prologue: 72 gate-constant quads into lane slots ----
    float gA, gB, gC, gD;
    float gA2 = 0.f, gB2 = 0.f, gC2 = 0.f, gD2 = 0.f;
    {
        const float* wl = w + lane * 3;
        float phi = wl[0], th = wl[1], om = wl[2];
        float c, s, ca, sa, cb, sb;
        __sincosf(0.5f * th, &s, &c);
        __sincosf(0.5f * (phi + om), &sa, &ca);
        __sincosf(0.5f * (phi - om), &sb, &cb);
        gA = c * ca; gB = c * sa; gC = s * cb; gD = s * sb;
        if (lane >= 52) {
            const float* wl2 = w + (lane + 8) * 3;
            float phi2 = wl2[0], th2 = wl2[1], om2 = wl2[2];
            float c2, s2q, ca2, sa2, cb2, sb2;
            __sincosf(0.5f * th2, &s2q, &c2);
            __sincosf(0.5f * (phi2 + om2), &sa2, &ca2);
            __sincosf(0.5f * (phi2 - om2), &sb2, &cb2);
            gA2 = c2 * ca2; gB2 = c2 * sa2; gC2 = s2q * cb2; gD2 = s2q * sb2;
        }
    }

    // ---- loop-invariant BYTE address bases (phys = swz(i) = i^((i>>4)&0xF)) ----
    const int ptAb = (t ^ ((t >> 4) & 0xF)) << 4;
    const int ptBb = (((((t & 0x1C0) << 3) | (t & 0x3F)) ^ ((t >> 4) & 0x3))) << 4;
    const int ptCb = (((((t & 0x1F8) << 3) | (t & 0x7)) ^ (((t >> 3) & 0x3) << 2))) << 4;
    const int ptDb = ((t << 3) ^ ((t >> 1) & 0xF)) << 4;
    int gv = t << 3;                  // g^-1 = suffix parity (GF(2)-linear)
    gv ^= gv >> 1; gv ^= gv >> 2; gv ^= gv >> 4; gv ^= gv >> 8; gv &= 0xFFF;
    const int ptDSb = (gv ^ ((gv >> 4) & 0xF)) << 4;

    A2 a0, a1, a2, a3, a4, a5, a6, a7;

    #pragma unroll 1
    for (int L = 0; L < NL; ++L) {
        const int   gb = (L == 5) ? 52 : L * 12;
        const float uA = (L == 5) ? gA2 : gA;
        const float uB = (L == 5) ? gB2 : gB;
        const float uC = (L == 5) ? gC2 : gC;
        const float uD = (L == 5) ? gD2 : gD;

        // ---- Pass A: state bits 11..9 (qubits 0..2) ----
        if (L == 0) {
            const int pcl = __popc(t);
            {   // element A init: amp_i = (-i)^popc(i) * prod(cos/sin)
                const float* xb = x + e0 * NQ;
                float c0,s0,c1,s1,c2,s2,c3,s3,c4,s4,c5,s5;
                float c6,s6,c7,s7,c8,s8,c9,s9,c10,s10,c11,s11;
                #define EMB(q) __sincosf(0.5f * xb[q], &s##q, &c##q);
                EMB(0) EMB(1) EMB(2) EMB(3) EMB(4)  EMB(5)
                EMB(6) EMB(7) EMB(8) EMB(9) EMB(10) EMB(11)
                float mlow = ((t & 1)   ? s11 : c11) * ((t & 2)   ? s10 : c10);
                mlow *= ((t & 4)   ? s9 : c9) * ((t & 8)   ? s8 : c8);
                mlow *= ((t & 16)  ? s7 : c7) * ((t & 32)  ? s6 : c6);
                mlow *= ((t & 64)  ? s5 : c5) * ((t & 128) ? s4 : c4);
                mlow *= ((t & 256) ? s3 : c3);
                const float e_0 = c1*c0, e_1 = s1*c0, e_2 = c1*s0, e_3 = s1*s0;
                const float f0 = c2*e_0, f1 = s2*e_0, f2 = c2*e_1, f3 = s2*e_1;
                const float f4 = c2*e_2, f5 = s2*e_2, f6 = c2*e_3, f7 = s2*e_3;
                INITA(0) INITA(1) INITA(2) INITA(3)
                INITA(4) INITA(5) INITA(6) INITA(7)
            }
            {   // element B init
                const float* xb = x + (e0 + 1) * NQ;
                float c0,s0,c1,s1,c2,s2,c3,s3,c4,s4,c5,s5;
                float c6,s6,c7,s7,c8,s8,c9,s9,c10,s10,c11,s11;
                EMB(0) EMB(1) EMB(2) EMB(3) EMB(4)  EMB(5)
                EMB(6) EMB(7) EMB(8) EMB(9) EMB(10) EMB(11)
                #undef EMB
                float mlow = ((t & 1)   ? s11 : c11) * ((t & 2)   ? s10 : c10);
                mlow *= ((t & 4)   ? s9 : c9) * ((t & 8)   ? s8 : c8);
                mlow *= ((t & 16)  ? s7 : c7) * ((t & 32)  ? s6 : c6);
                mlow *= ((t & 64)  ? s5 : c5) * ((t & 128) ? s4 : c4);
                mlow *= ((t & 256) ? s3 : c3);
                const float e_0 = c1*c0, e_1 = s1*c0, e_2 = c1*s0, e_3 = s1*s0;
                const float f0 = c2*e_0, f1 = s2*e_0, f2 = c2*e_1, f3 = s2*e_1;
                const float f4 = c2*e_2, f5 = s2*e_2, f6 = c2*e_3, f7 = s2*e_3;
                INITB(0) INITB(1) INITB(2) INITB(3)
                INITB(4) INITB(5) INITB(6) INITB(7)
            }
        } else {
            LD8(ADRA)
        }
        GATE(2, PK0) GATE(1, PK1) GATE(0, PK2)
        ST8(ADRA)
        __syncthreads();

        // ---- Pass B: state bits 8..6 (qubits 3..5) ----
        LD8(ADRB)
        GATE(5, PK0) GATE(4, PK1) GATE(3, PK2)
        ST8(ADRB)
        __syncthreads();

        // ---- Pass C: state bits 5..3 (qubits 6..8) ----
        LD8(ADRC)
        GATE(8, PK0) GATE(7, PK1) GATE(6, PK2)
        ST8(ADRC)
        __syncthreads();

        // ---- Pass D: state bits 2..0 (qubits 9..11) ----
        LD8(ADRD)
        GATE(11, PK0) GATE(10, PK1) GATE(9, PK2)
        if (L < NL - 1) {
            __syncthreads();          // all pass-D reads done before scatter
            ST8(ADRDS)                // Gray perm via g^-1 scatter
            __syncthreads();
        }
        // last layer: measure from regs (trailing perm preserves bit 11)
    }

    // ---- measurement: <Z> on qubit 0 = state bit 11 = t bit 8 ----
    float za = 0.0f, zb = 0.0f;
    za += a0.ar*a0.ar + a0.ai*a0.ai;  zb += a0.br*a0.br + a0.bi*a0.bi;
    za += a1.ar*a1.ar + a1.ai*a1.ai;  zb += a1.br*a1.br + a1.bi*a1.bi;
    za += a2.ar*a2.ar + a2.ai*a2.ai;  zb += a2.br*a2.br + a2.bi*a2.bi;
    za += a3.ar*a3.ar + a3.ai*a3.ai;  zb += a3.br*a3.br + a3.bi*a3.bi;
    za += a4.ar*a4.ar + a4.ai*a4.ai;  zb += a4.br*a4.br + a4.bi*a4.bi;
    za += a5.ar*a5.ar + a5.ai*a5.ai;  zb += a5.br*a5.br + a5.bi*a5.bi;
    za += a6.ar*a6.ar + a6.ai*a6.ai;  zb += a6.br*a6.br + a6.bi*a6.bi;
    za += a7.ar*a7.ar + a7.ai*a7.ai;  zb += a7.br*a7.br + a7.bi*a7.bi;

    const float sgn = (t & 256) ? -1.0f : 1.0f;
    za *= sgn; zb *= sgn;
    #pragma unroll
    for (int off = 32; off >= 1; off >>= 1) {
        za += __shfl_down(za, off);
        zb += __shfl_down(zb, off);
    }

    __syncthreads();                  // all pass-D reads done before st reuse
    float* red = (float*)st;
    if (lane == 0) { red[t >> 6] = za; red[8 + (t >> 6)] = zb; }
    __syncthreads();

    if (t == 0) {
        float zta = 0.0f, ztb = 0.0f;
        #pragma unroll
        for (int wv = 0; wv < 8; ++wv) { zta += red[wv]; ztb += red[8 + wv]; }
        out[2 * e0 + 0] = zta * hw[0] + hb[0];
        out[2 * e0 + 1] = zta * hw[1] + hb[1];
        out[2 * e0 + 2] = ztb * hw[0] + hb[0];
        out[2 * e0 + 3] = ztb * hw[1] + hb[1];
    }
}

extern "C" void kernel_launch(void* const* d_in, const int* in_sizes, int n_in,
                              void* d_out, int out_size, void* d_ws, size_t ws_size,
                              hipStream_t stream) {
    const float* x  = (const float*)d_in[0];
    const float* w  = (const float*)d_in[1];
    const float* hw = (const float*)d_in[2];
    const float* hb = (const float*)d_in[3];
    float* out = (float*)d_out;
    const int B = in_sizes[0] / NQ;   // 1024
    qsim_kernel<<<B / 2, TPB, 0, stream>>>(x, w, hw, hb, out);
}

// Round 12
// 40.851 us; speedup vs baseline: 1.3561x; 1.3561x over previous
//
#include <hip/hip_runtime.h>

#define NQ 12
#define NSTATE (1 << NQ)   // 4096 amps per batch element
#define NL 6
#define TPB 512            // 8 amp-slots/thread; TWO batch elements per slot

// Two batch elements per f4 LDS slot: (reA, imA, reB, imB) -> ds_*_b128.
// Layer 1 is folded into the init (Rot on a product state stays a product
// state; its CNOT Gray-perm is absorbed by index remap j = g(i)).
// Layer 6 is amputated: gates on qubits 1..11 commute out of <Z_0>
// ((U0 x V)^† Z0 (U0 x V) = (U0^† Z U0) x I), and the trailing Gray perm
// preserves bit 11 — so only gate 60 (layer-6 qubit 0) is applied.
// LDS layout phys = swz(i) = i ^ ((i>>4)&0xF); per-layer CNOT Gray perm
// new[i]=old[g(i)], g(i)=i^(i>>1), applied as g^-1 scatter at pass-D store.
// Gate constants live in lane slots, broadcast via v_readlane.

typedef float f4 __attribute__((ext_vector_type(4)));

struct A2 { float ar, ai, br, bi; };   // element A and B of one amp slot

__device__ __forceinline__ float RL(float v, int idx) {
    return __int_as_float(__builtin_amdgcn_readlane(__float_as_int(v), idx));
}

// Rot(phi,theta,omega): u00=(A,-B) u01=(-C,-D) u10=(C,-D) u11=(A,B)
__device__ __forceinline__ void bf2(A2& s0, A2& s1,
                                    float A, float B, float C, float D) {
    float n0r, n0i, n1r, n1i;
    n0r = fmaf(A, s0.ar, fmaf( B, s0.ai, fmaf(-C, s1.ar,  D * s1.ai)));
    n0i = fmaf(A, s0.ai, fmaf(-B, s0.ar, fmaf(-C, s1.ai, -D * s1.ar)));
    n1r = fmaf(C, s0.ar, fmaf( D, s0.ai, fmaf( A, s1.ar, -B * s1.ai)));
    n1i = fmaf(C, s0.ai, fmaf(-D, s0.ar, fmaf( A, s1.ai,  B * s1.ar)));
    s0.ar = n0r; s0.ai = n0i; s1.ar = n1r; s1.ai = n1i;
    n0r = fmaf(A, s0.br, fmaf( B, s0.bi, fmaf(-C, s1.br,  D * s1.bi)));
    n0i = fmaf(A, s0.bi, fmaf(-B, s0.br, fmaf(-C, s1.bi, -D * s1.br)));
    n1r = fmaf(C, s0.br, fmaf( D, s0.bi, fmaf( A, s1.br, -B * s1.bi)));
    n1i = fmaf(C, s0.bi, fmaf(-D, s0.br, fmaf( A, s1.bi,  B * s1.br)));
    s0.br = n0r; s0.bi = n0i; s1.br = n1r; s1.bi = n1i;
}

#define BF(i,j) bf2(a##i, a##j, A, B, C, D)
#define PK0 BF(0,1); BF(2,3); BF(4,5); BF(6,7);
#define PK1 BF(0,2); BF(1,3); BF(4,6); BF(5,7);
#define PK2 BF(0,4); BF(1,5); BF(2,6); BF(3,7);
#define GATE(qq, P) { const int gi = gb + (qq); \
    const float A = RL(gA, gi), B = RL(gB, gi), \
                C = RL(gC, gi), D = RL(gD, gi); P }

#define LDS4(off) (*(f4*)((char*)st + (off)))
#define LD1(r, ADR) { f4 v = LDS4(ADR(r)); \
    a##r.ar = v.x; a##r.ai = v.y; a##r.br = v.z; a##r.bi = v.w; }
#define ST1(r, ADR) { f4 v = {a##r.ar, a##r.ai, a##r.br, a##r.bi}; \
    LDS4(ADR(r)) = v; }
#define LD8(ADR) { LD1(0,ADR) LD1(1,ADR) LD1(2,ADR) LD1(3,ADR) \
                   LD1(4,ADR) LD1(5,ADR) LD1(6,ADR) LD1(7,ADR) }
#define ST8(ADR) { ST1(0,ADR) ST1(1,ADR) ST1(2,ADR) ST1(3,ADR) \
                   ST1(4,ADR) ST1(5,ADR) ST1(6,ADR) ST1(7,ADR) }

// Byte-address tilings (i = logical index, t = 9-bit thread, r = 3-bit reg):
// A: i=(r<<9)|t   B: i=t[8:6]<<9|r<<6|t[5:0]   C: i=t[8:3]<<6|r<<3|t[2:0]
// D: i=(t<<3)|r   D-scatter: phys = swz(g^-1(i))
#define ADRA(r)  (ptAb + ((r) << 13))                   // ds offset-immediate
#define ADRB(r)  (ptBb ^ (((r) << 10) ^ (((r) & 3) << 6)))
#define ADRC(r)  (ptCb ^ (((r) << 7) ^ (((r) >> 1) << 4)))
#define ADRD(r)  (ptDb ^ ((r) << 4))
#define GINV3(r) ((r) ^ ((r) >> 1) ^ ((r) >> 2))
#define ADRDS(r) (ptDSb ^ (GINV3(r) << 4))

// ---- init helpers (complex product state after layer 1) ----
// CM(n, x, y): complex n = x * y  (defines n##r, n##i)
#define CM(n, xr, xi, yr, yi) \
    const float n##r = fmaf(xr, yr, -(xi) * (yi)); \
    const float n##i = fmaf(xr, yi,  (xi) * (yr));
// gate-0..11 constants (uniform broadcasts, shared by both elements)
#define GCONST(q) const float A##q = RL(gA, q), B##q = RL(gB, q), \
                              C##q = RL(gC, q), D##q = RL(gD, q);
// v_q = Rot_q * (cos, -i sin): v_q[0] = (Ac-Ds, -Bc+Cs), v_q[1] = (Cc+Bs, -Dc-As)
#define VQDEF(q) \
    const float v##q##0r = fmaf(A##q, c##q, -(D##q) * s##q); \
    const float v##q##0i = fmaf(-(B##q), c##q,  (C##q) * s##q); \
    const float v##q##1r = fmaf(C##q, c##q,  (B##q) * s##q); \
    const float v##q##1i = fmaf(-(D##q), c##q, -(A##q) * s##q);
// qubit q factor selected by bit b of tj = t^(t>>1)
#define WSEL(q, b) \
    const float w##q##r = (tj & (1 << (b))) ? v##q##1r : v##q##0r; \
    const float w##q##i = (tj & (1 << (b))) ? v##q##1i : v##q##0i;
// amp_g = mm * Q[rp]   (g = reg index; RE/IM select element A or B members)
// NOTE: parameter is named g (NOT r) so the literal r/i suffixes paste right.
#define SETAMP(g, rp, mm, RE, IM) \
    a##g.RE = fmaf(mm##r, Q##rp##r, -(mm##i) * Q##rp##i); \
    a##g.IM = fmaf(mm##r, Q##rp##i,  (mm##i) * Q##rp##r);

__global__ __launch_bounds__(TPB) void qsim_kernel(
    const float* __restrict__ x,      // (B, 12)
    const float* __restrict__ w,      // (6, 12, 3)
    const float* __restrict__ hw,     // (2, 1)
    const float* __restrict__ hb,     // (2,)
    float* __restrict__ out)          // (B, 2)
{
    __shared__ f4 st[NSTATE];         // 64 KB: both elements, packed per slot

    const int t    = threadIdx.x;     // 9 bits
    const int lane = t & 63;
    const int e0   = blockIdx.x * 2;  // first batch element of this block

    // ---- prologue: gate-constant quads for gates 0..63 into lane slots ----
    // (init reads gates 0..11, layers 2..5 read 12..59, final reads 60.)
    float gA, gB, gC, gD;
    {
        const float* wl = w + lane * 3;
        float phi = wl[0], th = wl[1], om = wl[2];
        float c, s, ca, sa, cb, sb;
        __sincosf(0.5f * th, &s, &c);
        __sincosf(0.5f * (phi + om), &sa, &ca);
        __sincosf(0.5f * (phi - om), &sb, &cb);
        gA = c * ca; gB = c * sa; gC = s * cb; gD = s * sb;
    }

    // ---- loop-invariant BYTE address bases (phys = swz(i) = i^((i>>4)&0xF)) ----
    const int ptAb = (t ^ ((t >> 4) & 0xF)) << 4;
    const int ptBb = (((((t & 0x1C0) << 3) | (t & 0x3F)) ^ ((t >> 4) & 0x3))) << 4;
    const int ptCb = (((((t & 0x1F8) << 3) | (t & 0x7)) ^ (((t >> 3) & 0x3) << 2))) << 4;
    const int ptDb = ((t << 3) ^ ((t >> 1) & 0xF)) << 4;
    int gv = t << 3;                  // g^-1 = suffix parity (GF(2)-linear)
    gv ^= gv >> 1; gv ^= gv >> 2; gv ^= gv >> 4; gv ^= gv >> 8; gv &= 0xFFF;
    const int ptDSb = (gv ^ ((gv >> 4) & 0xF)) << 4;

    A2 a0, a1, a2, a3, a4, a5, a6, a7;

    #pragma unroll 1
    for (int k = 0; k < 4; ++k) {     // layers 2..5 (w[1]..w[4])
        const int gb = (k + 1) * 12;

        // ---- Pass A: state bits 11..9 (qubits 0..2) ----
        if (k == 0) {
            // init = post-layer-1 state (Rot x product = product), with
            // layer-1's Gray perm absorbed: amp at (r,t) = prod_q v_q[bit of j],
            // j = g(i): bits 7..0 from tj = t^(t>>1), bit 8 = t8 ^ (r&1),
            // bits 11..9 = rp = r ^ (r>>1).
            const int tj = t ^ (t >> 1);
            const int t8 = (t >> 8) & 1;
            GCONST(0)  GCONST(1)  GCONST(2)  GCONST(3)
            GCONST(4)  GCONST(5)  GCONST(6)  GCONST(7)
            GCONST(8)  GCONST(9)  GCONST(10) GCONST(11)
            {   // element A
                const float* xe = x + e0 * NQ;
                float c0,s0,c1,s1,c2,s2,c3,s3,c4,s4,c5,s5;
                float c6,s6,c7,s7,c8,s8,c9,s9,c10,s10,c11,s11;
                #define EMB(q) __sincosf(0.5f * xe[q], &s##q, &c##q);
                EMB(0) EMB(1) EMB(2) EMB(3) EMB(4)  EMB(5)
                EMB(6) EMB(7) EMB(8) EMB(9) EMB(10) EMB(11)
                // qubits 4..11 (j bits 7..0): select immediately, temps die
                VQDEF(4)  WSEL(4,7)  VQDEF(5)  WSEL(5,6)
                VQDEF(6)  WSEL(6,5)  VQDEF(7)  WSEL(7,4)
                VQDEF(8)  WSEL(8,3)  VQDEF(9)  WSEL(9,2)
                VQDEF(10) WSEL(10,1) VQDEF(11) WSEL(11,0)
                CM(m45, w4r, w4i, w5r, w5i)   CM(m67, w6r, w6i, w7r, w7i)
                CM(m89, w8r, w8i, w9r, w9i)   CM(mAB, w10r, w10i, w11r, w11i)
                CM(mP, m45r, m45i, m67r, m67i) CM(mQ, m89r, m89i, mABr, mABi)
                CM(mL, mPr, mPi, mQr, mQi)     // product over qubits 4..11
                // qubit 3 (j bit 8 = t8 ^ (r&1))
                VQDEF(3)
                const float w3ar = t8 ? v31r : v30r, w3ai = t8 ? v31i : v30i;
                const float w3br = t8 ? v30r : v31r, w3bi = t8 ? v30i : v31i;
                CM(q3a, mLr, mLi, w3ar, w3ai)  CM(q3b, mLr, mLi, w3br, w3bi)
                // qubits 0..2 (j bits 11..9): Q[z]=v0[z>>2]*v1[(z>>1)&1]*v2[z&1]
                VQDEF(0) VQDEF(1) VQDEF(2)
                CM(H0, v00r, v00i, v10r, v10i) CM(H1, v00r, v00i, v11r, v11i)
                CM(H2, v01r, v01i, v10r, v10i) CM(H3, v01r, v01i, v11r, v11i)
                CM(Q0, H0r, H0i, v20r, v20i)   CM(Q1, H0r, H0i, v21r, v21i)
                CM(Q2, H1r, H1i, v20r, v20i)   CM(Q3, H1r, H1i, v21r, v21i)
                CM(Q4, H2r, H2i, v20r, v20i)   CM(Q5, H2r, H2i, v21r, v21i)
                CM(Q6, H3r, H3i, v20r, v20i)   CM(Q7, H3r, H3i, v21r, v21i)
                SETAMP(0,0,q3a,ar,ai) SETAMP(1,1,q3b,ar,ai)
                SETAMP(2,3,q3a,ar,ai) SETAMP(3,2,q3b,ar,ai)
                SETAMP(4,6,q3a,ar,ai) SETAMP(5,7,q3b,ar,ai)
                SETAMP(6,5,q3a,ar,ai) SETAMP(7,4,q3b,ar,ai)
            }
            {   // element B
                const float* xe = x + (e0 + 1) * NQ;
                float c0,s0,c1,s1,c2,s2,c3,s3,c4,s4,c5,s5;
                float c6,s6,c7,s7,c8,s8,c9,s9,c10,s10,c11,s11;
                EMB(0) EMB(1) EMB(2) EMB(3) EMB(4)  EMB(5)
                EMB(6) EMB(7) EMB(8) EMB(9) EMB(10) EMB(11)
                #undef EMB
                VQDEF(4)  WSEL(4,7)  VQDEF(5)  WSEL(5,6)
                VQDEF(6)  WSEL(6,5)  VQDEF(7)  WSEL(7,4)
                VQDEF(8)  WSEL(8,3)  VQDEF(9)  WSEL(9,2)
                VQDEF(10) WSEL(10,1) VQDEF(11) WSEL(11,0)
                CM(m45, w4r, w4i, w5r, w5i)   CM(m67, w6r, w6i, w7r, w7i)
                CM(m89, w8r, w8i, w9r, w9i)   CM(mAB, w10r, w10i, w11r, w11i)
                CM(mP, m45r, m45i, m67r, m67i) CM(mQ, m89r, m89i, mABr, mABi)
                CM(mL, mPr, mPi, mQr, mQi)
                VQDEF(3)
                const float w3ar = t8 ? v31r : v30r, w3ai = t8 ? v31i : v30i;
                const float w3br = t8 ? v30r : v31r, w3bi = t8 ? v30i : v31i;
                CM(q3a, mLr, mLi, w3ar, w3ai)  CM(q3b, mLr, mLi, w3br, w3bi)
                VQDEF(0) VQDEF(1) VQDEF(2)
                CM(H0, v00r, v00i, v10r, v10i) CM(H1, v00r, v00i, v11r, v11i)
                CM(H2, v01r, v01i, v10r, v10i) CM(H3, v01r, v01i, v11r, v11i)
                CM(Q0, H0r, H0i, v20r, v20i)   CM(Q1, H0r, H0i, v21r, v21i)
                CM(Q2, H1r, H1i, v20r, v20i)   CM(Q3, H1r, H1i, v21r, v21i)
                CM(Q4, H2r, H2i, v20r, v20i)   CM(Q5, H2r, H2i, v21r, v21i)
                CM(Q6, H3r, H3i, v20r, v20i)   CM(Q7, H3r, H3i, v21r, v21i)
                SETAMP(0,0,q3a,br,bi) SETAMP(1,1,q3b,br,bi)
                SETAMP(2,3,q3a,br,bi) SETAMP(3,2,q3b,br,bi)
                SETAMP(4,6,q3a,br,bi) SETAMP(5,7,q3b,br,bi)
                SETAMP(6,5,q3a,br,bi) SETAMP(7,4,q3b,br,bi)
            }
        } else {
            LD8(ADRA)
        }
        GATE(2, PK0) GATE(1, PK1) GATE(0, PK2)
        ST8(ADRA)
        __syncthreads();

        // ---- Pass B: state bits 8..6 (qubits 3..5) ----
        LD8(ADRB)
        GATE(5, PK0) GATE(4, PK1) GATE(3, PK2)
        ST8(ADRB)
        __syncthreads();

        // ---- Pass C: state bits 5..3 (qubits 6..8) ----
        LD8(ADRC)
        GATE(8, PK0) GATE(7, PK1) GATE(6, PK2)
        ST8(ADRC)
        __syncthreads();

        // ---- Pass D: state bits 2..0 (qubits 9..11) + Gray scatter ----
        LD8(ADRD)
        GATE(11, PK0) GATE(10, PK1) GATE(9, PK2)
        __syncthreads();              // all pass-D reads done before scatter
        ST8(ADRDS)                    // Gray perm via g^-1 scatter
        __syncthreads();
    }

    // ---- Final layer (w[5]): only the qubit-0 gate (gate 60) survives
    //      inside <Z_0>; gates on qubits 1..11 and the trailing Gray perm
    //      commute with Z_0 and are dropped. Bit 11 = pass-A reg bit 2. ----
    LD8(ADRA)
    {
        const float A = RL(gA, 60), B = RL(gB, 60),
                    C = RL(gC, 60), D = RL(gD, 60);
        bf2(a0, a4, A, B, C, D); bf2(a1, a5, A, B, C, D);
        bf2(a2, a6, A, B, C, D); bf2(a3, a7, A, B, C, D);
    }

    // ---- measurement: <Z_0> = sum(|r<4|^2) - sum(|r>=4|^2) ----
    float za = 0.0f, zb = 0.0f;
    za += a0.ar*a0.ar + a0.ai*a0.ai;  zb += a0.br*a0.br + a0.bi*a0.bi;
    za += a1.ar*a1.ar + a1.ai*a1.ai;  zb += a1.br*a1.br + a1.bi*a1.bi;
    za += a2.ar*a2.ar + a2.ai*a2.ai;  zb += a2.br*a2.br + a2.bi*a2.bi;
    za += a3.ar*a3.ar + a3.ai*a3.ai;  zb += a3.br*a3.br + a3.bi*a3.bi;
    za -= a4.ar*a4.ar + a4.ai*a4.ai;  zb -= a4.br*a4.br + a4.bi*a4.bi;
    za -= a5.ar*a5.ar + a5.ai*a5.ai;  zb -= a5.br*a5.br + a5.bi*a5.bi;
    za -= a6.ar*a6.ar + a6.ai*a6.ai;  zb -= a6.br*a6.br + a6.bi*a6.bi;
    za -= a7.ar*a7.ar + a7.ai*a7.ai;  zb -= a7.br*a7.br + a7.bi*a7.bi;

    #pragma unroll
    for (int off = 32; off >= 1; off >>= 1) {
        za += __shfl_down(za, off);
        zb += __shfl_down(zb, off);
    }

    __syncthreads();                  // all final-pass reads done before reuse
    float* red = (float*)st;
    if (lane == 0) { red[t >> 6] = za; red[8 + (t >> 6)] = zb; }
    __syncthreads();

    if (t == 0) {
        float zta = 0.0f, ztb = 0.0f;
        #pragma unroll
        for (int wv = 0; wv < 8; ++wv) { zta += red[wv]; ztb += red[8 + wv]; }
        out[2 * e0 + 0] = zta * hw[0] + hb[0];
        out[2 * e0 + 1] = zta * hw[1] + hb[1];
        out[2 * e0 + 2] = ztb * hw[0] + hb[0];
        out[2 * e0 + 3] = ztb * hw[1] + hb[1];
    }
}

extern "C" void kernel_launch(void* const* d_in, const int* in_sizes, int n_in,
                              void* d_out, int out_size, void* d_ws, size_t ws_size,
                              hipStream_t stream) {
    const float* x  = (const float*)d_in[0];
    const float* w  = (const float*)d_in[1];
    const float* hw = (const float*)d_in[2];
    const float* hb = (const float*)d_in[3];
    float* out = (float*)d_out;
    const int B = in_sizes[0] / NQ;   // 1024
    qsim_kernel<<<B / 2, TPB, 0, stream>>>(x, w, hw, hb, out);
}